// Round 6
// baseline (2836.979 us; speedup 1.0000x reference)
//
#include <hip/hip_runtime.h>
#include <hip/hip_bf16.h>

#define HID 4096
#define NEMBD 64
#define NBATCH 32
#define NTIME 64
#define NVOCAB 256
#define G4 16384

typedef __attribute__((ext_vector_type(4))) float f32x4;
typedef __attribute__((ext_vector_type(8))) short s16x8;

__device__ __forceinline__ unsigned short f2bf(float f) {
  union { float f; unsigned u; } v; v.f = f;
  unsigned u = v.u + 0x7FFFu + ((v.u >> 16) & 1u);
  return (unsigned short)(u >> 16);
}

// A-fragment packed offset for a [32 rows][4096 k] bf16 matrix, chunked by 32k:
// chunk*1024 + tile512*(row>=16) + lane*8 + elem, lane = (row&15) | (((k>>3)&3)<<4)
__device__ __forceinline__ int apoff(int b, int j) {
  return ((j >> 5) << 10) | ((b >> 4) << 9) |
         (((b & 15) | (((j >> 3) & 3) << 4)) << 3) | (j & 7);
}

// ---------------- fused column-norm + pack into bf16 B-fragment order ----------------
// Each block owns a full-K strip of 16 columns. Pass 1: sum of squares per column
// (strip becomes L2-hot). Pass 2: scale + pack nch chunks of 32 k.
// colbase = (bid&3)*Cw + (bid>>S)*16 ; K = nch*32 ; dst tile = bid.
__global__ void pack2_k(const float* __restrict__ src, const float* __restrict__ g,
                        unsigned short* __restrict__ dst, int N, int Cw, int S, int nch) {
  int bid = blockIdx.x;
  int colbase = (bid & 3) * Cw + (bid >> S) * 16;
  int K = nch * 32;
  size_t dstbase = (size_t)bid * nch * 512;
  __shared__ float red[16][16];
  __shared__ float scS[16];
  __shared__ unsigned short tile[512];
  int tid = threadIdx.x;
  int col16 = tid & 15, kk = tid >> 4;  // kk in 0..15
  float sc = 1.f;
  if (g) {
    float s = 0.f;
    for (int k = kk; k < K; k += 16) {
      float v = src[(size_t)k * N + colbase + col16];
      s += v * v;
    }
    red[kk][col16] = s;
    __syncthreads();
    if (tid < 16) {
      float tot = 0.f;
#pragma unroll
      for (int q = 0; q < 16; ++q) tot += red[q][tid];
      scS[tid] = g[colbase + tid] / sqrtf(fmaxf(tot, 1e-12f));
    }
    __syncthreads();
    sc = scS[col16];
  }
  for (int c = 0; c < nch; ++c) {
    for (int h = 0; h < 2; ++h) {
      int kk2 = kk + h * 16;
      int k = c * 32 + kk2;
      float v = src[(size_t)k * N + colbase + col16] * sc;
      int l = col16 | (((kk2 >> 3) & 3) << 4);
      tile[l * 8 + (kk2 & 7)] = f2bf(v);
    }
    __syncthreads();
    if (tid < 64)
      ((s16x8*)(dst + dstbase + (size_t)c * 512))[tid] = ((s16x8*)tile)[tid];
    __syncthreads();
  }
}

// ---------------- embed X and pack x_t [32][64] into A-fragment order per t ----------
__global__ void xepack_k(const int* __restrict__ X, const float* __restrict__ embd,
                         unsigned short* __restrict__ xe) {
  int t = blockIdx.x;
  int tid = threadIdx.x;
  int l = tid & 63, tile = (tid >> 6) & 1, c2 = tid >> 7;
  int b = tile * 16 + (l & 15);
  int row = X[b * NTIME + t];
  int k0 = 32 * c2 + 8 * (l >> 4);
  size_t off = (size_t)t * 2048 + c2 * 1024 + tile * 512 + l * 8;
  for (int j = 0; j < 8; ++j) xe[off + j] = f2bf(embd[row * NEMBD + k0 + j]);
}

// ---------------- init states -------------------------------------------------------
__global__ void init_k(const float* __restrict__ S, float* __restrict__ cst,
                       float* __restrict__ hst, unsigned short* __restrict__ hpk) {
  int e = blockIdx.x * 256 + threadIdx.x;
  if (e < NBATCH * HID) {
    float c = S[e], h = S[NBATCH * HID + e];
    cst[e] = c; hst[e] = h;
    int b = e >> 12, j = e & 4095;
    hpk[apoff(b, j)] = f2bf(h);
  }
}

#define MFMA(a, b, c) __builtin_amdgcn_mfma_f32_16x16x32_bf16(a, b, c, 0, 0, 0)

// ---------------- phase 1 of step t: hm = h@wmhn (K split 16 ways), m = xm*hm --------
__global__ __launch_bounds__(1024)
void ph1_k(const unsigned short* __restrict__ wmhp, const unsigned short* __restrict__ wmxp,
           const unsigned short* __restrict__ xe, const unsigned short* __restrict__ hpk,
           unsigned short* __restrict__ mpk, int t) {
  const int g = blockIdx.x;
  const int tid = threadIdx.x;
  const int w = tid >> 6, l = tid & 63;
  const int lo = l & 15, hi = l >> 4;

  __shared__ float part[16][32][16];
  __shared__ float xmS[32][16];

  const s16x8* wmh_g = (const s16x8*)(wmhp + (size_t)g * 128 * 512);
  const s16x8* wmx_g = (const s16x8*)(wmxp + (size_t)g * 2 * 512);
  const s16x8* hp = (const s16x8*)hpk;

  f32x4 a0 = {0.f, 0.f, 0.f, 0.f}, a1 = {0.f, 0.f, 0.f, 0.f};
#pragma unroll
  for (int q = 0; q < 8; ++q) {
    int cc = w * 8 + q;
    s16x8 bf = wmh_g[cc * 64 + l];
    a0 = MFMA(hp[cc * 128 + l], bf, a0);
    a1 = MFMA(hp[cc * 128 + 64 + l], bf, a1);
  }
#pragma unroll
  for (int r = 0; r < 4; ++r) {
    part[w][4 * hi + r][lo] = a0[r];
    part[w][16 + 4 * hi + r][lo] = a1[r];
  }
  if (w == 0) {  // xm = x_t @ wmxn (K=64)
    f32x4 x0 = {0.f, 0.f, 0.f, 0.f}, x1 = {0.f, 0.f, 0.f, 0.f};
    const s16x8* xep = (const s16x8*)(xe + (size_t)t * 2048);
#pragma unroll
    for (int c2 = 0; c2 < 2; ++c2) {
      s16x8 bf = wmx_g[c2 * 64 + l];
      x0 = MFMA(xep[c2 * 128 + l], bf, x0);
      x1 = MFMA(xep[c2 * 128 + 64 + l], bf, x1);
    }
#pragma unroll
    for (int r = 0; r < 4; ++r) {
      xmS[4 * hi + r][lo] = x0[r];
      xmS[16 + 4 * hi + r][lo] = x1[r];
    }
  }
  __syncthreads();
  if (tid < 256) {
    const int eb = tid >> 3, c0 = (tid & 7) * 2;
    const int ej = g * 16 + c0;
    float hm0 = 0.f, hm1 = 0.f;
#pragma unroll
    for (int k = 0; k < 16; ++k) {
      hm0 += part[k][eb][c0];
      hm1 += part[k][eb][c0 + 1];
    }
    unsigned pk = (unsigned)f2bf(xmS[eb][c0] * hm0) |
                  ((unsigned)f2bf(xmS[eb][c0 + 1] * hm1) << 16);
    ((unsigned*)mpk)[apoff(eb, ej) >> 1] = pk;
  }
}

// ---------------- phase 2 of step t: z = x@wxn + m@whn + b ; gates ; update ----------
// hflat is written in A-fragment-packed order: tile = b*4 + (t>>4) of 16 rows (r16=t&15)
__global__ __launch_bounds__(1024)
void ph2_k(const unsigned short* __restrict__ whp, const unsigned short* __restrict__ wxp,
           const unsigned short* __restrict__ xe, const float* __restrict__ bias,
           const float* __restrict__ Mm, const unsigned short* __restrict__ mpk,
           unsigned short* __restrict__ hpk, float* __restrict__ cst,
           float* __restrict__ hst, unsigned short* __restrict__ hflat,
           float* __restrict__ out, int t) {
  const int g = blockIdx.x;
  const int tid = threadIdx.x;
  const int w = tid >> 6, l = tid & 63;
  const int lo = l & 15, hi = l >> 4;
  const int gate = w & 3, ks = w >> 2;

  __shared__ float part[16][32][16];

  const s16x8* wh_w = (const s16x8*)(whp + (size_t)(g * 4 + gate) * 128 * 512);
  const s16x8* wx_w = (const s16x8*)(wxp + (size_t)(g * 4 + gate) * 2 * 512);
  const s16x8* mp = (const s16x8*)mpk;

  f32x4 z0 = {0.f, 0.f, 0.f, 0.f}, z1 = {0.f, 0.f, 0.f, 0.f};
#pragma unroll 4
  for (int q = 0; q < 32; ++q) {
    int cc = ks * 32 + q;
    s16x8 bf = wh_w[cc * 64 + l];
    z0 = MFMA(mp[cc * 128 + l], bf, z0);
    z1 = MFMA(mp[cc * 128 + 64 + l], bf, z1);
  }
  if (ks == 0) {  // x @ wxn contribution (K=64)
    const s16x8* xep = (const s16x8*)(xe + (size_t)t * 2048);
#pragma unroll
    for (int c2 = 0; c2 < 2; ++c2) {
      s16x8 bf = wx_w[c2 * 64 + l];
      z0 = MFMA(xep[c2 * 128 + l], bf, z0);
      z1 = MFMA(xep[c2 * 128 + 64 + l], bf, z1);
    }
  }
#pragma unroll
  for (int r = 0; r < 4; ++r) {
    part[w][4 * hi + r][lo] = z0[r];
    part[w][16 + 4 * hi + r][lo] = z1[r];
  }
  __syncthreads();
  if (tid < 256) {
    const int eb = tid >> 3, c0 = (tid & 7) * 2;
    const int ej = g * 16 + c0;
    float iv0 = part[0][eb][c0] + part[4][eb][c0] + part[8][eb][c0] + part[12][eb][c0] + bias[ej];
    float iv1 = part[0][eb][c0+1] + part[4][eb][c0+1] + part[8][eb][c0+1] + part[12][eb][c0+1] + bias[ej + 1];
    float fv0 = part[1][eb][c0] + part[5][eb][c0] + part[9][eb][c0] + part[13][eb][c0] + bias[4096 + ej];
    float fv1 = part[1][eb][c0+1] + part[5][eb][c0+1] + part[9][eb][c0+1] + part[13][eb][c0+1] + bias[4096 + ej + 1];
    float ov0 = part[2][eb][c0] + part[6][eb][c0] + part[10][eb][c0] + part[14][eb][c0] + bias[8192 + ej];
    float ov1 = part[2][eb][c0+1] + part[6][eb][c0+1] + part[10][eb][c0+1] + part[14][eb][c0+1] + bias[8192 + ej + 1];
    float uv0 = part[3][eb][c0] + part[7][eb][c0] + part[11][eb][c0] + part[15][eb][c0] + bias[12288 + ej];
    float uv1 = part[3][eb][c0+1] + part[7][eb][c0+1] + part[11][eb][c0+1] + part[15][eb][c0+1] + bias[12288 + ej + 1];
    iv0 = 1.f / (1.f + __expf(-iv0)); iv1 = 1.f / (1.f + __expf(-iv1));
    fv0 = 1.f / (1.f + __expf(-fv0)); fv1 = 1.f / (1.f + __expf(-fv1));
    ov0 = 1.f / (1.f + __expf(-ov0)); ov1 = 1.f / (1.f + __expf(-ov1));
    uv0 = tanhf(uv0); uv1 = tanhf(uv1);
    size_t sj = (size_t)eb * HID + ej;
    float cp0 = cst[sj], cp1 = cst[sj + 1];
    float hp0 = hst[sj], hp1 = hst[sj + 1];
    float ct0 = fv0 * cp0 + iv0 * uv0, ct1 = fv1 * cp1 + iv1 * uv1;
    float ht0 = ov0 * tanhf(ct0), ht1 = ov1 * tanhf(ct1);
    float mt = Mm[eb * NTIME + t];
    float cn0 = ct0 * mt + cp0 * (1.f - mt), cn1 = ct1 * mt + cp1 * (1.f - mt);
    float hn0 = ht0 * mt + hp0 * (1.f - mt), hn1 = ht1 * mt + hp1 * (1.f - mt);
    cst[sj] = cn0; cst[sj + 1] = cn1;
    hst[sj] = hn0; hst[sj + 1] = hn1;
    out[((size_t)t * NBATCH + eb) * HID + ej] = cn0;
    out[((size_t)t * NBATCH + eb) * HID + ej + 1] = cn1;
    unsigned hpack = (unsigned)f2bf(hn0) | ((unsigned)f2bf(hn1) << 16);
    // packed A-fragment write for logits: tile = eb*4 + (t>>4), row-in-tile = t&15
    {
      int tle = eb * 4 + (t >> 4);
      int r16 = t & 15;
      int kk2 = ej & 31;
      int lane2 = r16 | (((kk2 >> 3) & 3) << 4);
      size_t hoff = (size_t)tle * 65536 + (size_t)(ej >> 5) * 512 + lane2 * 8 + (kk2 & 7);
      ((unsigned*)hflat)[hoff >> 1] = hpack;
    }
    ((unsigned*)hpk)[apoff(eb, ej) >> 1] = hpack;
    if (t == NTIME - 1) {
      out[(size_t)NTIME * NBATCH * HID + sj] = cn0;
      out[(size_t)NTIME * NBATCH * HID + sj + 1] = cn1;
      out[(size_t)NTIME * NBATCH * HID + NBATCH * HID + sj] = hn0;
      out[(size_t)NTIME * NBATCH * HID + NBATCH * HID + sj + 1] = hn1;
    }
  }
}

// ---------------- logits = hflat @ w_out + b_out, packed-A ([2048,4096]x[4096,256]) --
// grid: 128 row-tiles x 2 col-halves; block 256 = 4 waves; wave w: 2 col tiles
__global__ __launch_bounds__(256)
void logits_k(const unsigned short* __restrict__ hpA,
              const unsigned short* __restrict__ woutp,
              const float* __restrict__ bout, float* __restrict__ out) {
  int tle = blockIdx.x >> 1, ch = blockIdx.x & 1;
  int tid = threadIdx.x, w = tid >> 6, l = tid & 63;
  int lo = l & 15, hi = l >> 4;
  const s16x8* ap = (const s16x8*)(hpA + (size_t)tle * 65536);
  const s16x8* wp = (const s16x8*)woutp;
  f32x4 acc[2] = {{0.f,0.f,0.f,0.f},{0.f,0.f,0.f,0.f}};
  const int nt0 = ch * 8 + w * 2;
#pragma unroll 4
  for (int c = 0; c < 128; ++c) {
    s16x8 af = ap[c * 64 + l];
    acc[0] = MFMA(af, wp[((nt0 + 0) * 128 + c) * 64 + l], acc[0]);
    acc[1] = MFMA(af, wp[((nt0 + 1) * 128 + c) * 64 + l], acc[1]);
  }
  int r0 = tle * 16;
#pragma unroll
  for (int q = 0; q < 2; ++q) {
    int col = (nt0 + q) * 16 + lo;
    float bo = bout[col];
#pragma unroll
    for (int r = 0; r < 4; ++r)
      out[(size_t)(r0 + 4 * hi + r) * NVOCAB + col] = acc[q][r] + bo;
  }
}

extern "C" void kernel_launch(void* const* d_in, const int* in_sizes, int n_in,
                              void* d_out, int out_size, void* d_ws, size_t ws_size,
                              hipStream_t stream) {
  const int*   X    = (const int*)d_in[0];
  const float* Mm   = (const float*)d_in[1];
  const float* S    = (const float*)d_in[2];
  const float* embd = (const float*)d_in[3];
  const float* wx   = (const float*)d_in[4];
  const float* wh   = (const float*)d_in[5];
  const float* wmx  = (const float*)d_in[6];
  const float* wmh  = (const float*)d_in[7];
  const float* b    = (const float*)d_in[8];
  const float* gx   = (const float*)d_in[9];
  const float* gh   = (const float*)d_in[10];
  const float* gmx  = (const float*)d_in[11];
  const float* gmh  = (const float*)d_in[12];
  const float* wout = (const float*)d_in[13];
  const float* bout = (const float*)d_in[14];
  float* out = (float*)d_out;
  char* ws = (char*)d_ws;

  size_t cur = 0;
  auto alloc = [&](size_t bytes) { size_t o = cur; cur += (bytes + 255) & ~size_t(255); return o; };
  unsigned short* WHP   = (unsigned short*)(ws + alloc((size_t)1024 * 128 * 512 * 2)); // 128MB
  unsigned short* WMHP  = (unsigned short*)(ws + alloc((size_t)256 * 128 * 512 * 2));  // 32MB
  unsigned short* WXP   = (unsigned short*)(ws + alloc((size_t)1024 * 2 * 512 * 2));   // 2MB
  unsigned short* WMXP  = (unsigned short*)(ws + alloc((size_t)256 * 2 * 512 * 2));    // 0.5MB
  unsigned short* WOUTP = (unsigned short*)(ws + alloc((size_t)16 * 128 * 512 * 2));   // 2MB
  unsigned short* XE    = (unsigned short*)(ws + alloc((size_t)64 * 2048 * 2));        // 256KB
  unsigned short* MPK   = (unsigned short*)(ws + alloc((size_t)32 * 4096 * 2));        // 256KB
  unsigned short* HPK   = (unsigned short*)(ws + alloc((size_t)32 * 4096 * 2));        // 256KB
  float* CST            = (float*)(ws + alloc((size_t)32 * 4096 * 4));
  float* HST            = (float*)(ws + alloc((size_t)32 * 4096 * 4));
  unsigned short* HFLAT = (unsigned short*)(ws + alloc((size_t)2048 * 4096 * 2));      // 16MB
  (void)ws_size; (void)in_sizes; (void)n_in; (void)out_size;

  // fused column-norm + pack into bf16 fragment order
  pack2_k<<<1024, 256, 0, stream>>>(wh,   gh,  WHP,   G4,    4096, 2, 128);
  pack2_k<<<256,  256, 0, stream>>>(wmh,  gmh, WMHP,  HID,   0,    0, 128);
  pack2_k<<<1024, 256, 0, stream>>>(wx,   gx,  WXP,   G4,    4096, 2, 2);
  pack2_k<<<256,  256, 0, stream>>>(wmx,  gmx, WMXP,  HID,   0,    0, 2);
  pack2_k<<<16,   256, 0, stream>>>(wout, nullptr, WOUTP, NVOCAB, 0, 0, 128);

  xepack_k<<<64, 256, 0, stream>>>(X, embd, XE);
  init_k<<<512, 256, 0, stream>>>(S, CST, HST, HPK);

  // 64 steps, 2 kernels per step — stream ordering replaces the grid barrier
  for (int t = 0; t < NTIME; ++t) {
    ph1_k<<<256, 1024, 0, stream>>>(WMHP, WMXP, XE, HPK, MPK, t);
    ph2_k<<<256, 1024, 0, stream>>>(WHP, WXP, XE, b, Mm, MPK, HPK, CST, HST, HFLAT, out, t);
  }

  logits_k<<<256, 256, 0, stream>>>(HFLAT, WOUTP, bout,
                                    out + (size_t)NTIME * NBATCH * HID + 2 * NBATCH * HID);
}

// Round 7
// 2429.803 us; speedup vs baseline: 1.1676x; 1.1676x over previous
//
#include <hip/hip_runtime.h>
#include <hip/hip_bf16.h>

#define HID 4096
#define NEMBD 64
#define NBATCH 32
#define NTIME 64
#define NVOCAB 256
#define G4 16384

typedef __attribute__((ext_vector_type(4))) float f32x4;
typedef __attribute__((ext_vector_type(8))) short s16x8;

__device__ __forceinline__ unsigned short f2bf(float f) {
  union { float f; unsigned u; } v; v.f = f;
  unsigned u = v.u + 0x7FFFu + ((v.u >> 16) & 1u);
  return (unsigned short)(u >> 16);
}

// A-fragment packed offset for a [32 rows][4096 k] bf16 matrix, chunked by 32k:
// chunk*1024 + tile512*(row>=16) + lane*8 + elem, lane = (row&15) | (((k>>3)&3)<<4)
__device__ __forceinline__ int apoff(int b, int j) {
  return ((j >> 5) << 10) | ((b >> 4) << 9) |
         (((b & 15) | (((j >> 3) & 3) << 4)) << 3) | (j & 7);
}

// ---------------- stage 1: partial column sums of squares (deterministic K-split) ----
__global__ void colsum_k(const float* __restrict__ w, float* __restrict__ ss,
                         int K, int N, int KS) {
  int col = threadIdx.x & 63, kg = threadIdx.x >> 6;
  int j = blockIdx.x * 64 + col;
  int kper = K / KS;
  int k0 = blockIdx.y * kper;
  float s = 0.f;
#pragma unroll 4
  for (int k = k0 + kg; k < k0 + kper; k += 4) {
    float v = w[(size_t)k * N + j];
    s += v * v;
  }
  __shared__ float red[4][64];
  red[kg][col] = s;
  __syncthreads();
  if (threadIdx.x < 64)
    ss[(size_t)blockIdx.y * N + j] = red[0][col] + red[1][col] + red[2][col] + red[3][col];
}

// ---------------- pack fp32 [K][N] column-slice into bf16 B-fragment order -----------
// tile bid: colbase=(bid&3)*Cw+(bid>>S)*16; nch chunks of 32k split over gridDim.y.
// Scale finalized from KS partial sums (ss may be null -> scale 1).
__global__ void pack_k(const float* __restrict__ src, const float* __restrict__ ss,
                       const float* __restrict__ g, unsigned short* __restrict__ dst,
                       int N, int Cw, int S, int nch, int KS) {
  int bid = blockIdx.x;
  int colbase = (bid & 3) * Cw + (bid >> S) * 16;
  int cper = nch / gridDim.y;
  int c0 = blockIdx.y * cper;
  size_t dstbase = (size_t)bid * nch * 512 + (size_t)c0 * 512;
  __shared__ unsigned short tile[512];
  int tid = threadIdx.x;
  int col16 = tid & 15, kk = tid >> 4;
  float sc = 1.f;
  if (ss) {
    float t = 0.f;
    for (int q = 0; q < KS; ++q) t += ss[(size_t)q * N + colbase + col16];
    sc = g[colbase + col16] / sqrtf(fmaxf(t, 1e-12f));
  }
  for (int c = c0; c < c0 + cper; ++c) {
    for (int h = 0; h < 2; ++h) {
      int kk2 = kk + h * 16;
      int k = c * 32 + kk2;
      float v = src[(size_t)k * N + colbase + col16] * sc;
      int l = col16 | (((kk2 >> 3) & 3) << 4);
      tile[l * 8 + (kk2 & 7)] = f2bf(v);
    }
    __syncthreads();
    if (tid < 64)
      ((s16x8*)(dst + dstbase + (size_t)(c - c0) * 512))[tid] = ((s16x8*)tile)[tid];
    __syncthreads();
  }
}

// ---------------- embed X and pack x_t [32][64] into A-fragment order per t ----------
__global__ void xepack_k(const int* __restrict__ X, const float* __restrict__ embd,
                         unsigned short* __restrict__ xe) {
  int t = blockIdx.x;
  int tid = threadIdx.x;
  int l = tid & 63, tile = (tid >> 6) & 1, c2 = tid >> 7;
  int b = tile * 16 + (l & 15);
  int row = X[b * NTIME + t];
  int k0 = 32 * c2 + 8 * (l >> 4);
  size_t off = (size_t)t * 2048 + c2 * 1024 + tile * 512 + l * 8;
  for (int j = 0; j < 8; ++j) xe[off + j] = f2bf(embd[row * NEMBD + k0 + j]);
}

// ---------------- init states -------------------------------------------------------
__global__ void init_k(const float* __restrict__ S, float* __restrict__ cst,
                       float* __restrict__ hst, unsigned short* __restrict__ hpk) {
  int e = blockIdx.x * 256 + threadIdx.x;
  if (e < NBATCH * HID) {
    float c = S[e], h = S[NBATCH * HID + e];
    cst[e] = c; hst[e] = h;
    int b = e >> 12, j = e & 4095;
    hpk[apoff(b, j)] = f2bf(h);
  }
}

#define MFMA(a, b, c) __builtin_amdgcn_mfma_f32_16x16x32_bf16(a, b, c, 0, 0, 0)

// ---------------- phase 1 of step t: hm = h@wmhn (K split 16 ways), m = xm*hm --------
__global__ __launch_bounds__(1024)
void ph1_k(const unsigned short* __restrict__ wmhp, const unsigned short* __restrict__ wmxp,
           const unsigned short* __restrict__ xe, const unsigned short* __restrict__ hpk,
           unsigned short* __restrict__ mpk, int t) {
  const int g = blockIdx.x;
  const int tid = threadIdx.x;
  const int w = tid >> 6, l = tid & 63;
  const int lo = l & 15, hi = l >> 4;

  __shared__ float part[16][32][16];
  __shared__ float xmS[32][16];

  const s16x8* wmh_g = (const s16x8*)(wmhp + (size_t)g * 128 * 512);
  const s16x8* wmx_g = (const s16x8*)(wmxp + (size_t)g * 2 * 512);
  const s16x8* hp = (const s16x8*)hpk;

  f32x4 a0 = {0.f, 0.f, 0.f, 0.f}, a1 = {0.f, 0.f, 0.f, 0.f};
#pragma unroll
  for (int q = 0; q < 8; ++q) {
    int cc = w * 8 + q;
    s16x8 bf = wmh_g[cc * 64 + l];
    a0 = MFMA(hp[cc * 128 + l], bf, a0);
    a1 = MFMA(hp[cc * 128 + 64 + l], bf, a1);
  }
#pragma unroll
  for (int r = 0; r < 4; ++r) {
    part[w][4 * hi + r][lo] = a0[r];
    part[w][16 + 4 * hi + r][lo] = a1[r];
  }
  if (w == 0) {  // xm = x_t @ wmxn (K=64)
    f32x4 x0 = {0.f, 0.f, 0.f, 0.f}, x1 = {0.f, 0.f, 0.f, 0.f};
    const s16x8* xep = (const s16x8*)(xe + (size_t)t * 2048);
#pragma unroll
    for (int c2 = 0; c2 < 2; ++c2) {
      s16x8 bf = wmx_g[c2 * 64 + l];
      x0 = MFMA(xep[c2 * 128 + l], bf, x0);
      x1 = MFMA(xep[c2 * 128 + 64 + l], bf, x1);
    }
#pragma unroll
    for (int r = 0; r < 4; ++r) {
      xmS[4 * hi + r][lo] = x0[r];
      xmS[16 + 4 * hi + r][lo] = x1[r];
    }
  }
  __syncthreads();
  if (tid < 256) {
    const int eb = tid >> 3, c0 = (tid & 7) * 2;
    const int ej = g * 16 + c0;
    float hm0 = 0.f, hm1 = 0.f;
#pragma unroll
    for (int k = 0; k < 16; ++k) {
      hm0 += part[k][eb][c0];
      hm1 += part[k][eb][c0 + 1];
    }
    unsigned pk = (unsigned)f2bf(xmS[eb][c0] * hm0) |
                  ((unsigned)f2bf(xmS[eb][c0 + 1] * hm1) << 16);
    ((unsigned*)mpk)[apoff(eb, ej) >> 1] = pk;
  }
}

// ---------------- phase 2 of step t: z = x@wxn + m@whn + b ; gates ; update ----------
// wh streamed with an explicit 4-deep chunk rotation (12 x 16B loads in flight).
__global__ __launch_bounds__(1024, 4)
void ph2_k(const unsigned short* __restrict__ whp, const unsigned short* __restrict__ wxp,
           const unsigned short* __restrict__ xe, const float* __restrict__ bias,
           const float* __restrict__ Mm, const unsigned short* __restrict__ mpk,
           unsigned short* __restrict__ hpk, float* __restrict__ cst,
           float* __restrict__ hst, unsigned short* __restrict__ hflat,
           float* __restrict__ out, int t) {
  const int g = blockIdx.x;
  const int tid = threadIdx.x;
  const int w = tid >> 6, l = tid & 63;
  const int lo = l & 15, hi = l >> 4;
  const int gate = w & 3, ks = w >> 2;

  __shared__ float part[16][32][16];

  const s16x8* wh_w = (const s16x8*)(whp + (size_t)(g * 4 + gate) * 128 * 512);
  const s16x8* wx_w = (const s16x8*)(wxp + (size_t)(g * 4 + gate) * 2 * 512);
  const s16x8* mp = (const s16x8*)mpk;

  f32x4 z0 = {0.f, 0.f, 0.f, 0.f}, z1 = {0.f, 0.f, 0.f, 0.f};
  const int cb = ks * 32;
  {
    s16x8 wbuf[4], pa[4], pb[4];
#pragma unroll
    for (int q = 0; q < 4; ++q) {
      wbuf[q] = wh_w[(cb + q) * 64 + l];
      pa[q] = mp[(cb + q) * 128 + l];
      pb[q] = mp[(cb + q) * 128 + 64 + l];
    }
#pragma unroll
    for (int q = 0; q < 32; ++q) {
      const int r = q & 3;
      s16x8 bf = wbuf[r], af = pa[r], gf = pb[r];
      if (q < 28) {
        wbuf[r] = wh_w[(cb + q + 4) * 64 + l];
        pa[r] = mp[(cb + q + 4) * 128 + l];
        pb[r] = mp[(cb + q + 4) * 128 + 64 + l];
      }
      z0 = MFMA(af, bf, z0);
      z1 = MFMA(gf, bf, z1);
    }
  }
  if (ks == 0) {  // x @ wxn contribution (K=64)
    const s16x8* xep = (const s16x8*)(xe + (size_t)t * 2048);
#pragma unroll
    for (int c2 = 0; c2 < 2; ++c2) {
      s16x8 bf = wx_w[c2 * 64 + l];
      z0 = MFMA(xep[c2 * 128 + l], bf, z0);
      z1 = MFMA(xep[c2 * 128 + 64 + l], bf, z1);
    }
  }
#pragma unroll
  for (int r = 0; r < 4; ++r) {
    part[w][4 * hi + r][lo] = z0[r];
    part[w][16 + 4 * hi + r][lo] = z1[r];
  }
  __syncthreads();
  if (tid < 256) {
    const int eb = tid >> 3, c0 = (tid & 7) * 2;
    const int ej = g * 16 + c0;
    float iv0 = part[0][eb][c0] + part[4][eb][c0] + part[8][eb][c0] + part[12][eb][c0] + bias[ej];
    float iv1 = part[0][eb][c0+1] + part[4][eb][c0+1] + part[8][eb][c0+1] + part[12][eb][c0+1] + bias[ej + 1];
    float fv0 = part[1][eb][c0] + part[5][eb][c0] + part[9][eb][c0] + part[13][eb][c0] + bias[4096 + ej];
    float fv1 = part[1][eb][c0+1] + part[5][eb][c0+1] + part[9][eb][c0+1] + part[13][eb][c0+1] + bias[4096 + ej + 1];
    float ov0 = part[2][eb][c0] + part[6][eb][c0] + part[10][eb][c0] + part[14][eb][c0] + bias[8192 + ej];
    float ov1 = part[2][eb][c0+1] + part[6][eb][c0+1] + part[10][eb][c0+1] + part[14][eb][c0+1] + bias[8192 + ej + 1];
    float uv0 = part[3][eb][c0] + part[7][eb][c0] + part[11][eb][c0] + part[15][eb][c0] + bias[12288 + ej];
    float uv1 = part[3][eb][c0+1] + part[7][eb][c0+1] + part[11][eb][c0+1] + part[15][eb][c0+1] + bias[12288 + ej + 1];
    iv0 = 1.f / (1.f + __expf(-iv0)); iv1 = 1.f / (1.f + __expf(-iv1));
    fv0 = 1.f / (1.f + __expf(-fv0)); fv1 = 1.f / (1.f + __expf(-fv1));
    ov0 = 1.f / (1.f + __expf(-ov0)); ov1 = 1.f / (1.f + __expf(-ov1));
    uv0 = tanhf(uv0); uv1 = tanhf(uv1);
    size_t sj = (size_t)eb * HID + ej;
    float cp0 = cst[sj], cp1 = cst[sj + 1];
    float hp0 = hst[sj], hp1 = hst[sj + 1];
    float ct0 = fv0 * cp0 + iv0 * uv0, ct1 = fv1 * cp1 + iv1 * uv1;
    float ht0 = ov0 * tanhf(ct0), ht1 = ov1 * tanhf(ct1);
    float mt = Mm[eb * NTIME + t];
    float cn0 = ct0 * mt + cp0 * (1.f - mt), cn1 = ct1 * mt + cp1 * (1.f - mt);
    float hn0 = ht0 * mt + hp0 * (1.f - mt), hn1 = ht1 * mt + hp1 * (1.f - mt);
    cst[sj] = cn0; cst[sj + 1] = cn1;
    hst[sj] = hn0; hst[sj + 1] = hn1;
    out[((size_t)t * NBATCH + eb) * HID + ej] = cn0;
    out[((size_t)t * NBATCH + eb) * HID + ej + 1] = cn1;
    unsigned hpack = (unsigned)f2bf(hn0) | ((unsigned)f2bf(hn1) << 16);
    // packed A-fragment write for logits: tile = eb*4 + (t>>4), row-in-tile = t&15
    {
      int tle = eb * 4 + (t >> 4);
      int r16 = t & 15;
      int kk2 = ej & 31;
      int lane2 = r16 | (((kk2 >> 3) & 3) << 4);
      size_t hoff = (size_t)tle * 65536 + (size_t)(ej >> 5) * 512 + lane2 * 8 + (kk2 & 7);
      ((unsigned*)hflat)[hoff >> 1] = hpack;
    }
    ((unsigned*)hpk)[apoff(eb, ej) >> 1] = hpack;
    if (t == NTIME - 1) {
      out[(size_t)NTIME * NBATCH * HID + sj] = cn0;
      out[(size_t)NTIME * NBATCH * HID + sj + 1] = cn1;
      out[(size_t)NTIME * NBATCH * HID + NBATCH * HID + sj] = hn0;
      out[(size_t)NTIME * NBATCH * HID + NBATCH * HID + sj + 1] = hn1;
    }
  }
}

// ---------------- logits = hflat @ w_out + b_out, packed-A ([2048,4096]x[4096,256]) --
// grid: 128 row-tiles x 2 col-halves; block 256 = 4 waves; wave w: 2 col tiles
__global__ __launch_bounds__(256)
void logits_k(const unsigned short* __restrict__ hpA,
              const unsigned short* __restrict__ woutp,
              const float* __restrict__ bout, float* __restrict__ out) {
  int tle = blockIdx.x >> 1, ch = blockIdx.x & 1;
  int tid = threadIdx.x, w = tid >> 6, l = tid & 63;
  int lo = l & 15, hi = l >> 4;
  const s16x8* ap = (const s16x8*)(hpA + (size_t)tle * 65536);
  const s16x8* wp = (const s16x8*)woutp;
  f32x4 acc[2] = {{0.f,0.f,0.f,0.f},{0.f,0.f,0.f,0.f}};
  const int nt0 = ch * 8 + w * 2;
#pragma unroll 4
  for (int c = 0; c < 128; ++c) {
    s16x8 af = ap[c * 64 + l];
    acc[0] = MFMA(af, wp[((nt0 + 0) * 128 + c) * 64 + l], acc[0]);
    acc[1] = MFMA(af, wp[((nt0 + 1) * 128 + c) * 64 + l], acc[1]);
  }
  int r0 = tle * 16;
#pragma unroll
  for (int q = 0; q < 2; ++q) {
    int col = (nt0 + q) * 16 + lo;
    float bo = bout[col];
#pragma unroll
    for (int r = 0; r < 4; ++r)
      out[(size_t)(r0 + 4 * hi + r) * NVOCAB + col] = acc[q][r] + bo;
  }
}

extern "C" void kernel_launch(void* const* d_in, const int* in_sizes, int n_in,
                              void* d_out, int out_size, void* d_ws, size_t ws_size,
                              hipStream_t stream) {
  const int*   X    = (const int*)d_in[0];
  const float* Mm   = (const float*)d_in[1];
  const float* S    = (const float*)d_in[2];
  const float* embd = (const float*)d_in[3];
  const float* wx   = (const float*)d_in[4];
  const float* wh   = (const float*)d_in[5];
  const float* wmx  = (const float*)d_in[6];
  const float* wmh  = (const float*)d_in[7];
  const float* b    = (const float*)d_in[8];
  const float* gx   = (const float*)d_in[9];
  const float* gh   = (const float*)d_in[10];
  const float* gmx  = (const float*)d_in[11];
  const float* gmh  = (const float*)d_in[12];
  const float* wout = (const float*)d_in[13];
  const float* bout = (const float*)d_in[14];
  float* out = (float*)d_out;
  char* ws = (char*)d_ws;

  size_t cur = 0;
  auto alloc = [&](size_t bytes) { size_t o = cur; cur += (bytes + 255) & ~size_t(255); return o; };
  unsigned short* WHP   = (unsigned short*)(ws + alloc((size_t)1024 * 128 * 512 * 2)); // 128MB
  unsigned short* WMHP  = (unsigned short*)(ws + alloc((size_t)256 * 128 * 512 * 2));  // 32MB
  unsigned short* WXP   = (unsigned short*)(ws + alloc((size_t)1024 * 2 * 512 * 2));   // 2MB
  unsigned short* WMXP  = (unsigned short*)(ws + alloc((size_t)256 * 2 * 512 * 2));    // 0.5MB
  unsigned short* WOUTP = (unsigned short*)(ws + alloc((size_t)16 * 128 * 512 * 2));   // 2MB
  unsigned short* XE    = (unsigned short*)(ws + alloc((size_t)64 * 2048 * 2));        // 256KB
  unsigned short* MPK   = (unsigned short*)(ws + alloc((size_t)32 * 4096 * 2));        // 256KB
  unsigned short* HPK   = (unsigned short*)(ws + alloc((size_t)32 * 4096 * 2));        // 256KB
  float* CST            = (float*)(ws + alloc((size_t)32 * 4096 * 4));
  float* HST            = (float*)(ws + alloc((size_t)32 * 4096 * 4));
  unsigned short* HFLAT = (unsigned short*)(ws + alloc((size_t)2048 * 4096 * 2));      // 16MB
  float* SSH            = (float*)(ws + alloc((size_t)8 * 16384 * 4));
  float* SSMH           = (float*)(ws + alloc((size_t)8 * 4096 * 4));
  float* SSX            = (float*)(ws + alloc((size_t)16384 * 4));
  float* SSMX           = (float*)(ws + alloc((size_t)4096 * 4));
  (void)ws_size; (void)in_sizes; (void)n_in; (void)out_size;

  // stage-1 column sums of squares (coalesced, parallel, deterministic)
  colsum_k<<<dim3(256, 8), 256, 0, stream>>>(wh,  SSH,  HID, G4,  8);
  colsum_k<<<dim3(64, 8),  256, 0, stream>>>(wmh, SSMH, HID, HID, 8);
  colsum_k<<<dim3(256, 1), 256, 0, stream>>>(wx,  SSX,  NEMBD, G4,  1);
  colsum_k<<<dim3(64, 1),  256, 0, stream>>>(wmx, SSMX, NEMBD, HID, 1);

  // pack weights into bf16 fragment order (scale finalized in-kernel)
  pack_k<<<dim3(1024, 8), 256, 0, stream>>>(wh,  SSH,  gh,  WHP,  G4,  4096, 2, 128, 8);
  pack_k<<<dim3(256, 4),  256, 0, stream>>>(wmh, SSMH, gmh, WMHP, HID, 0,    0, 128, 8);
  pack_k<<<dim3(1024, 1), 256, 0, stream>>>(wx,  SSX,  gx,  WXP,  G4,  4096, 2, 2,   1);
  pack_k<<<dim3(256, 1),  256, 0, stream>>>(wmx, SSMX, gmx, WMXP, HID, 0,    0, 2,   1);
  pack_k<<<dim3(16, 1),   256, 0, stream>>>(wout, nullptr, nullptr, WOUTP, NVOCAB, 0, 0, 128, 0);

  xepack_k<<<64, 256, 0, stream>>>(X, embd, XE);
  init_k<<<512, 256, 0, stream>>>(S, CST, HST, HPK);

  // 64 steps, 2 kernels per step — stream ordering replaces the grid barrier
  for (int t = 0; t < NTIME; ++t) {
    ph1_k<<<256, 1024, 0, stream>>>(WMHP, WMXP, XE, HPK, MPK, t);
    ph2_k<<<256, 1024, 0, stream>>>(WHP, WXP, XE, b, Mm, MPK, HPK, CST, HST, HFLAT, out, t);
  }

  logits_k<<<256, 256, 0, stream>>>(HFLAT, WOUTP, bout,
                                    out + (size_t)NTIME * NBATCH * HID + 2 * NBATCH * HID);
}

// Round 8
// 2422.463 us; speedup vs baseline: 1.1711x; 1.0030x over previous
//
#include <hip/hip_runtime.h>
#include <hip/hip_bf16.h>

#define HID 4096
#define NEMBD 64
#define NBATCH 32
#define NTIME 64
#define NVOCAB 256
#define G4 16384

typedef __attribute__((ext_vector_type(4))) float f32x4;
typedef __attribute__((ext_vector_type(8))) short s16x8;

__device__ __forceinline__ unsigned short f2bf(float f) {
  union { float f; unsigned u; } v; v.f = f;
  unsigned u = v.u + 0x7FFFu + ((v.u >> 16) & 1u);
  return (unsigned short)(u >> 16);
}

// A-fragment packed offset for a [32 rows][4096 k] bf16 matrix, chunked by 32k:
// chunk*1024 + tile512*(row>=16) + lane*8 + elem, lane = (row&15) | (((k>>3)&3)<<4)
__device__ __forceinline__ int apoff(int b, int j) {
  return ((j >> 5) << 10) | ((b >> 4) << 9) |
         (((b & 15) | (((j >> 3) & 3) << 4)) << 3) | (j & 7);
}

// ---------------- stage 1: partial column sums of squares (deterministic K-split) ----
__global__ void colsum_k(const float* __restrict__ w, float* __restrict__ ss,
                         int K, int N, int KS) {
  int col = threadIdx.x & 63, kg = threadIdx.x >> 6;
  int j = blockIdx.x * 64 + col;
  int kper = K / KS;
  int k0 = blockIdx.y * kper;
  float s = 0.f;
#pragma unroll 4
  for (int k = k0 + kg; k < k0 + kper; k += 4) {
    float v = w[(size_t)k * N + j];
    s += v * v;
  }
  __shared__ float red[4][64];
  red[kg][col] = s;
  __syncthreads();
  if (threadIdx.x < 64)
    ss[(size_t)blockIdx.y * N + j] = red[0][col] + red[1][col] + red[2][col] + red[3][col];
}

// ---------------- pack fp32 [K][N] column-slice into bf16 B-fragment order -----------
// tile bid: colbase=(bid&3)*Cw+(bid>>S)*16; nch chunks of 32k split over gridDim.y.
// Scale finalized from KS partial sums (ss may be null -> scale 1).
__global__ void pack_k(const float* __restrict__ src, const float* __restrict__ ss,
                       const float* __restrict__ g, unsigned short* __restrict__ dst,
                       int N, int Cw, int S, int nch, int KS) {
  int bid = blockIdx.x;
  int colbase = (bid & 3) * Cw + (bid >> S) * 16;
  int cper = nch / gridDim.y;
  int c0 = blockIdx.y * cper;
  size_t dstbase = (size_t)bid * nch * 512 + (size_t)c0 * 512;
  __shared__ unsigned short tile[512];
  int tid = threadIdx.x;
  int col16 = tid & 15, kk = tid >> 4;
  float sc = 1.f;
  if (ss) {
    float t = 0.f;
    for (int q = 0; q < KS; ++q) t += ss[(size_t)q * N + colbase + col16];
    sc = g[colbase + col16] / sqrtf(fmaxf(t, 1e-12f));
  }
  for (int c = c0; c < c0 + cper; ++c) {
    for (int h = 0; h < 2; ++h) {
      int kk2 = kk + h * 16;
      int k = c * 32 + kk2;
      float v = src[(size_t)k * N + colbase + col16] * sc;
      int l = col16 | (((kk2 >> 3) & 3) << 4);
      tile[l * 8 + (kk2 & 7)] = f2bf(v);
    }
    __syncthreads();
    if (tid < 64)
      ((s16x8*)(dst + dstbase + (size_t)(c - c0) * 512))[tid] = ((s16x8*)tile)[tid];
    __syncthreads();
  }
}

// ---------------- embed X and pack x_t [32][64] into A-fragment order per t ----------
__global__ void xepack_k(const int* __restrict__ X, const float* __restrict__ embd,
                         unsigned short* __restrict__ xe) {
  int t = blockIdx.x;
  int tid = threadIdx.x;
  int l = tid & 63, tile = (tid >> 6) & 1, c2 = tid >> 7;
  int b = tile * 16 + (l & 15);
  int row = X[b * NTIME + t];
  int k0 = 32 * c2 + 8 * (l >> 4);
  size_t off = (size_t)t * 2048 + c2 * 1024 + tile * 512 + l * 8;
  for (int j = 0; j < 8; ++j) xe[off + j] = f2bf(embd[row * NEMBD + k0 + j]);
}

// ---------------- init states -------------------------------------------------------
__global__ void init_k(const float* __restrict__ S, float* __restrict__ cst,
                       float* __restrict__ hst, unsigned short* __restrict__ hpk) {
  int e = blockIdx.x * 256 + threadIdx.x;
  if (e < NBATCH * HID) {
    float c = S[e], h = S[NBATCH * HID + e];
    cst[e] = c; hst[e] = h;
    int b = e >> 12, j = e & 4095;
    hpk[apoff(b, j)] = f2bf(h);
  }
}

#define MFMA(a, b, c) __builtin_amdgcn_mfma_f32_16x16x32_bf16(a, b, c, 0, 0, 0)

// ---------------- phase 1 of step t: hm = h@wmhn (K split 16 ways), m = xm*hm --------
// 4-deep named-rotation pipeline (12 x 16B loads in flight), 512-thread epilogue.
__global__ __launch_bounds__(1024, 4)
void ph1_k(const unsigned short* __restrict__ wmhp, const unsigned short* __restrict__ wmxp,
           const unsigned short* __restrict__ xe, const unsigned short* __restrict__ hpk,
           unsigned short* __restrict__ mpk, int t) {
  const int g = blockIdx.x;
  const int tid = threadIdx.x;
  const int w = tid >> 6, l = tid & 63;
  const int lo = l & 15, hi = l >> 4;

  __shared__ float part[16][32][16];
  __shared__ float xmS[32][16];

  const s16x8* wmh_g = (const s16x8*)(wmhp + (size_t)g * 128 * 512);
  const s16x8* wmx_g = (const s16x8*)(wmxp + (size_t)g * 2 * 512);
  const s16x8* hp = (const s16x8*)hpk;

  f32x4 a0 = {0.f, 0.f, 0.f, 0.f}, a1 = {0.f, 0.f, 0.f, 0.f};
  const int cb = w * 8;
  {
    s16x8 wbuf[4], pa[4], pb[4];
#pragma unroll
    for (int q = 0; q < 4; ++q) {
      wbuf[q] = wmh_g[(cb + q) * 64 + l];
      pa[q] = hp[(cb + q) * 128 + l];
      pb[q] = hp[(cb + q) * 128 + 64 + l];
    }
#pragma unroll
    for (int q = 0; q < 8; ++q) {
      const int r = q & 3;
      s16x8 bf = wbuf[r], af = pa[r], gf = pb[r];
      if (q < 4) {
        wbuf[r] = wmh_g[(cb + q + 4) * 64 + l];
        pa[r] = hp[(cb + q + 4) * 128 + l];
        pb[r] = hp[(cb + q + 4) * 128 + 64 + l];
      }
      a0 = MFMA(af, bf, a0);
      a1 = MFMA(gf, bf, a1);
    }
  }
#pragma unroll
  for (int r = 0; r < 4; ++r) {
    part[w][4 * hi + r][lo] = a0[r];
    part[w][16 + 4 * hi + r][lo] = a1[r];
  }
  if (w == 0) {  // xm = x_t @ wmxn (K=64)
    f32x4 x0 = {0.f, 0.f, 0.f, 0.f}, x1 = {0.f, 0.f, 0.f, 0.f};
    const s16x8* xep = (const s16x8*)(xe + (size_t)t * 2048);
#pragma unroll
    for (int c2 = 0; c2 < 2; ++c2) {
      s16x8 bf = wmx_g[c2 * 64 + l];
      x0 = MFMA(xep[c2 * 128 + l], bf, x0);
      x1 = MFMA(xep[c2 * 128 + 64 + l], bf, x1);
    }
#pragma unroll
    for (int r = 0; r < 4; ++r) {
      xmS[4 * hi + r][lo] = x0[r];
      xmS[16 + 4 * hi + r][lo] = x1[r];
    }
  }
  __syncthreads();
  if (tid < 512) {
    const int eb = tid >> 4, c = tid & 15;
    const int ej = g * 16 + c;
    float hm = 0.f;
#pragma unroll
    for (int k = 0; k < 16; ++k) hm += part[k][eb][c];
    mpk[apoff(eb, ej)] = f2bf(xmS[eb][c] * hm);
  }
}

// ---------------- phase 2 of step t: z = x@wxn + m@whn + b ; gates ; update ----------
// wh streamed with an explicit 4-deep chunk rotation; 512-thread epilogue.
__global__ __launch_bounds__(1024, 4)
void ph2_k(const unsigned short* __restrict__ whp, const unsigned short* __restrict__ wxp,
           const unsigned short* __restrict__ xe, const float* __restrict__ bias,
           const float* __restrict__ Mm, const unsigned short* __restrict__ mpk,
           unsigned short* __restrict__ hpk, float* __restrict__ cst,
           float* __restrict__ hst, unsigned short* __restrict__ hflat,
           float* __restrict__ out, int t) {
  const int g = blockIdx.x;
  const int tid = threadIdx.x;
  const int w = tid >> 6, l = tid & 63;
  const int lo = l & 15, hi = l >> 4;
  const int gate = w & 3, ks = w >> 2;

  __shared__ float part[16][32][16];

  const s16x8* wh_w = (const s16x8*)(whp + (size_t)(g * 4 + gate) * 128 * 512);
  const s16x8* wx_w = (const s16x8*)(wxp + (size_t)(g * 4 + gate) * 2 * 512);
  const s16x8* mp = (const s16x8*)mpk;

  f32x4 z0 = {0.f, 0.f, 0.f, 0.f}, z1 = {0.f, 0.f, 0.f, 0.f};
  const int cb = ks * 32;
  {
    s16x8 wbuf[4], pa[4], pb[4];
#pragma unroll
    for (int q = 0; q < 4; ++q) {
      wbuf[q] = wh_w[(cb + q) * 64 + l];
      pa[q] = mp[(cb + q) * 128 + l];
      pb[q] = mp[(cb + q) * 128 + 64 + l];
    }
#pragma unroll
    for (int q = 0; q < 32; ++q) {
      const int r = q & 3;
      s16x8 bf = wbuf[r], af = pa[r], gf = pb[r];
      if (q < 28) {
        wbuf[r] = wh_w[(cb + q + 4) * 64 + l];
        pa[r] = mp[(cb + q + 4) * 128 + l];
        pb[r] = mp[(cb + q + 4) * 128 + 64 + l];
      }
      z0 = MFMA(af, bf, z0);
      z1 = MFMA(gf, bf, z1);
    }
  }
  if (ks == 0) {  // x @ wxn contribution (K=64)
    const s16x8* xep = (const s16x8*)(xe + (size_t)t * 2048);
#pragma unroll
    for (int c2 = 0; c2 < 2; ++c2) {
      s16x8 bf = wx_w[c2 * 64 + l];
      z0 = MFMA(xep[c2 * 128 + l], bf, z0);
      z1 = MFMA(xep[c2 * 128 + 64 + l], bf, z1);
    }
  }
#pragma unroll
  for (int r = 0; r < 4; ++r) {
    part[w][4 * hi + r][lo] = z0[r];
    part[w][16 + 4 * hi + r][lo] = z1[r];
  }
  __syncthreads();
  if (tid < 512) {
    const int eb = tid >> 4, c = tid & 15;
    const int ej = g * 16 + c;
    float iv = part[0][eb][c] + part[4][eb][c] + part[8][eb][c] + part[12][eb][c] + bias[ej];
    float fv = part[1][eb][c] + part[5][eb][c] + part[9][eb][c] + part[13][eb][c] + bias[4096 + ej];
    float ov = part[2][eb][c] + part[6][eb][c] + part[10][eb][c] + part[14][eb][c] + bias[8192 + ej];
    float uv = part[3][eb][c] + part[7][eb][c] + part[11][eb][c] + part[15][eb][c] + bias[12288 + ej];
    iv = 1.f / (1.f + __expf(-iv));
    fv = 1.f / (1.f + __expf(-fv));
    ov = 1.f / (1.f + __expf(-ov));
    uv = tanhf(uv);
    size_t sj = (size_t)eb * HID + ej;
    float cp = cst[sj], hpv = hst[sj];
    float ct = fv * cp + iv * uv;
    float ht = ov * tanhf(ct);
    float mt = Mm[eb * NTIME + t];
    float cn = ct * mt + cp * (1.f - mt);
    float hn = ht * mt + hpv * (1.f - mt);
    cst[sj] = cn;
    hst[sj] = hn;
    out[((size_t)t * NBATCH + eb) * HID + ej] = cn;
    unsigned short hb = f2bf(hn);
    // packed A-fragment write for logits: tile = eb*4 + (t>>4), row-in-tile = t&15
    {
      int tle = eb * 4 + (t >> 4);
      int r16 = t & 15;
      int kk2 = ej & 31;
      int lane2 = r16 | (((kk2 >> 3) & 3) << 4);
      hflat[(size_t)tle * 65536 + (size_t)(ej >> 5) * 512 + lane2 * 8 + (kk2 & 7)] = hb;
    }
    hpk[apoff(eb, ej)] = hb;
    if (t == NTIME - 1) {
      out[(size_t)NTIME * NBATCH * HID + sj] = cn;
      out[(size_t)NTIME * NBATCH * HID + NBATCH * HID + sj] = hn;
    }
  }
}

// ---------------- logits = hflat @ w_out + b_out, packed-A ([2048,4096]x[4096,256]) --
// grid: 128 row-tiles x 2 col-halves; block 256 = 4 waves; wave w: 2 col tiles
__global__ __launch_bounds__(256)
void logits_k(const unsigned short* __restrict__ hpA,
              const unsigned short* __restrict__ woutp,
              const float* __restrict__ bout, float* __restrict__ out) {
  int tle = blockIdx.x >> 1, ch = blockIdx.x & 1;
  int tid = threadIdx.x, w = tid >> 6, l = tid & 63;
  int lo = l & 15, hi = l >> 4;
  const s16x8* ap = (const s16x8*)(hpA + (size_t)tle * 65536);
  const s16x8* wp = (const s16x8*)woutp;
  f32x4 acc[2] = {{0.f,0.f,0.f,0.f},{0.f,0.f,0.f,0.f}};
  const int nt0 = ch * 8 + w * 2;
#pragma unroll 4
  for (int c = 0; c < 128; ++c) {
    s16x8 af = ap[c * 64 + l];
    acc[0] = MFMA(af, wp[((nt0 + 0) * 128 + c) * 64 + l], acc[0]);
    acc[1] = MFMA(af, wp[((nt0 + 1) * 128 + c) * 64 + l], acc[1]);
  }
  int r0 = tle * 16;
#pragma unroll
  for (int q = 0; q < 2; ++q) {
    int col = (nt0 + q) * 16 + lo;
    float bo = bout[col];
#pragma unroll
    for (int r = 0; r < 4; ++r)
      out[(size_t)(r0 + 4 * hi + r) * NVOCAB + col] = acc[q][r] + bo;
  }
}

extern "C" void kernel_launch(void* const* d_in, const int* in_sizes, int n_in,
                              void* d_out, int out_size, void* d_ws, size_t ws_size,
                              hipStream_t stream) {
  const int*   X    = (const int*)d_in[0];
  const float* Mm   = (const float*)d_in[1];
  const float* S    = (const float*)d_in[2];
  const float* embd = (const float*)d_in[3];
  const float* wx   = (const float*)d_in[4];
  const float* wh   = (const float*)d_in[5];
  const float* wmx  = (const float*)d_in[6];
  const float* wmh  = (const float*)d_in[7];
  const float* b    = (const float*)d_in[8];
  const float* gx   = (const float*)d_in[9];
  const float* gh   = (const float*)d_in[10];
  const float* gmx  = (const float*)d_in[11];
  const float* gmh  = (const float*)d_in[12];
  const float* wout = (const float*)d_in[13];
  const float* bout = (const float*)d_in[14];
  float* out = (float*)d_out;
  char* ws = (char*)d_ws;

  size_t cur = 0;
  auto alloc = [&](size_t bytes) { size_t o = cur; cur += (bytes + 255) & ~size_t(255); return o; };
  unsigned short* WHP   = (unsigned short*)(ws + alloc((size_t)1024 * 128 * 512 * 2)); // 128MB
  unsigned short* WMHP  = (unsigned short*)(ws + alloc((size_t)256 * 128 * 512 * 2));  // 32MB
  unsigned short* WXP   = (unsigned short*)(ws + alloc((size_t)1024 * 2 * 512 * 2));   // 2MB
  unsigned short* WMXP  = (unsigned short*)(ws + alloc((size_t)256 * 2 * 512 * 2));    // 0.5MB
  unsigned short* WOUTP = (unsigned short*)(ws + alloc((size_t)16 * 128 * 512 * 2));   // 2MB
  unsigned short* XE    = (unsigned short*)(ws + alloc((size_t)64 * 2048 * 2));        // 256KB
  unsigned short* MPK   = (unsigned short*)(ws + alloc((size_t)32 * 4096 * 2));        // 256KB
  unsigned short* HPK   = (unsigned short*)(ws + alloc((size_t)32 * 4096 * 2));        // 256KB
  float* CST            = (float*)(ws + alloc((size_t)32 * 4096 * 4));
  float* HST            = (float*)(ws + alloc((size_t)32 * 4096 * 4));
  unsigned short* HFLAT = (unsigned short*)(ws + alloc((size_t)2048 * 4096 * 2));      // 16MB
  float* SSH            = (float*)(ws + alloc((size_t)8 * 16384 * 4));
  float* SSMH           = (float*)(ws + alloc((size_t)8 * 4096 * 4));
  float* SSX            = (float*)(ws + alloc((size_t)16384 * 4));
  float* SSMX           = (float*)(ws + alloc((size_t)4096 * 4));
  (void)ws_size; (void)in_sizes; (void)n_in; (void)out_size;

  // stage-1 column sums of squares (coalesced, parallel, deterministic)
  colsum_k<<<dim3(256, 8), 256, 0, stream>>>(wh,  SSH,  HID, G4,  8);
  colsum_k<<<dim3(64, 8),  256, 0, stream>>>(wmh, SSMH, HID, HID, 8);
  colsum_k<<<dim3(256, 1), 256, 0, stream>>>(wx,  SSX,  NEMBD, G4,  1);
  colsum_k<<<dim3(64, 1),  256, 0, stream>>>(wmx, SSMX, NEMBD, HID, 1);

  // pack weights into bf16 fragment order (scale finalized in-kernel)
  pack_k<<<dim3(1024, 8), 256, 0, stream>>>(wh,  SSH,  gh,  WHP,  G4,  4096, 2, 128, 8);
  pack_k<<<dim3(256, 4),  256, 0, stream>>>(wmh, SSMH, gmh, WMHP, HID, 0,    0, 128, 8);
  pack_k<<<dim3(1024, 1), 256, 0, stream>>>(wx,  SSX,  gx,  WXP,  G4,  4096, 2, 2,   1);
  pack_k<<<dim3(256, 1),  256, 0, stream>>>(wmx, SSMX, gmx, WMXP, HID, 0,    0, 2,   1);
  pack_k<<<dim3(16, 1),   256, 0, stream>>>(wout, nullptr, nullptr, WOUTP, NVOCAB, 0, 0, 128, 0);

  xepack_k<<<64, 256, 0, stream>>>(X, embd, XE);
  init_k<<<512, 256, 0, stream>>>(S, CST, HST, HPK);

  // 64 steps, 2 kernels per step — stream ordering replaces the grid barrier
  for (int t = 0; t < NTIME; ++t) {
    ph1_k<<<256, 1024, 0, stream>>>(WMHP, WMXP, XE, HPK, MPK, t);
    ph2_k<<<256, 1024, 0, stream>>>(WHP, WXP, XE, b, Mm, MPK, HPK, CST, HST, HFLAT, out, t);
  }

  logits_k<<<256, 256, 0, stream>>>(HFLAT, WOUTP, bout,
                                    out + (size_t)NTIME * NBATCH * HID + 2 * NBATCH * HID);
}

// Round 9
// 2421.272 us; speedup vs baseline: 1.1717x; 1.0005x over previous
//
#include <hip/hip_runtime.h>
#include <hip/hip_bf16.h>

#define HID 4096
#define NEMBD 64
#define NBATCH 32
#define NTIME 64
#define NVOCAB 256
#define G4 16384

typedef __attribute__((ext_vector_type(4))) float f32x4;
typedef __attribute__((ext_vector_type(8))) short s16x8;

__device__ __forceinline__ unsigned short f2bf(float f) {
  union { float f; unsigned u; } v; v.f = f;
  unsigned u = v.u + 0x7FFFu + ((v.u >> 16) & 1u);
  return (unsigned short)(u >> 16);
}

// A-fragment packed offset for a [32 rows][4096 k] bf16 matrix, chunked by 32k:
// chunk*1024 + tile512*(row>=16) + lane*8 + elem, lane = (row&15) | (((k>>3)&3)<<4)
__device__ __forceinline__ int apoff(int b, int j) {
  return ((j >> 5) << 10) | ((b >> 4) << 9) |
         (((b & 15) | (((j >> 3) & 3) << 4)) << 3) | (j & 7);
}

// ---------------- fused one-pass: pack RAW fp32 [K][N] strip into bf16 B-fragments ---
// and produce weight-norm scale sc[j] = g[j]/sqrt(sum_k w[k][j]^2) (scale applied at
// runtime in the consumers). Block bid: colbase=(bid&3)*Cw+(bid>>S)*16; K = nch*32.
__global__ void packs_k(const float* __restrict__ src, const float* __restrict__ g,
                        unsigned short* __restrict__ dst, float* __restrict__ sc,
                        int N, int Cw, int S, int nch) {
  int bid = blockIdx.x;
  int colbase = (bid & 3) * Cw + (bid >> S) * 16;
  size_t dstbase = (size_t)bid * nch * 512;
  __shared__ unsigned short tile[512];
  __shared__ float red[16][16];
  int tid = threadIdx.x;
  int col16 = tid & 15, kk = tid >> 4;  // kk in 0..15
  float s = 0.f;
  for (int c = 0; c < nch; ++c) {
    float v0 = src[(size_t)(c * 32 + kk) * N + colbase + col16];
    float v1 = src[(size_t)(c * 32 + kk + 16) * N + colbase + col16];
    s += v0 * v0 + v1 * v1;
    int l0 = col16 | (((kk >> 3) & 3) << 4);
    int l1 = col16 | ((((kk + 16) >> 3) & 3) << 4);
    tile[l0 * 8 + (kk & 7)] = f2bf(v0);
    tile[l1 * 8 + (kk & 7)] = f2bf(v1);
    __syncthreads();
    if (tid < 64)
      ((s16x8*)(dst + dstbase + (size_t)c * 512))[tid] = ((s16x8*)tile)[tid];
    __syncthreads();
  }
  if (g) {
    red[kk][col16] = s;
    __syncthreads();
    if (tid < 16) {
      float tot = 0.f;
#pragma unroll
      for (int q = 0; q < 16; ++q) tot += red[q][tid];
      sc[colbase + tid] = g[colbase + tid] / sqrtf(fmaxf(tot, 1e-12f));
    }
  }
}

// ---------------- embed X and pack x_t [32][64] into A-fragment order per t ----------
__global__ void xepack_k(const int* __restrict__ X, const float* __restrict__ embd,
                         unsigned short* __restrict__ xe) {
  int t = blockIdx.x;
  int tid = threadIdx.x;
  int l = tid & 63, tile = (tid >> 6) & 1, c2 = tid >> 7;
  int b = tile * 16 + (l & 15);
  int row = X[b * NTIME + t];
  int k0 = 32 * c2 + 8 * (l >> 4);
  size_t off = (size_t)t * 2048 + c2 * 1024 + tile * 512 + l * 8;
  for (int j = 0; j < 8; ++j) xe[off + j] = f2bf(embd[row * NEMBD + k0 + j]);
}

// ---------------- init states -------------------------------------------------------
__global__ void init_k(const float* __restrict__ S, float* __restrict__ cst,
                       float* __restrict__ hst, unsigned short* __restrict__ hpk) {
  int e = blockIdx.x * 256 + threadIdx.x;
  if (e < NBATCH * HID) {
    float c = S[e], h = S[NBATCH * HID + e];
    cst[e] = c; hst[e] = h;
    int b = e >> 12, j = e & 4095;
    hpk[apoff(b, j)] = f2bf(h);
  }
}

#define MFMA(a, b, c) __builtin_amdgcn_mfma_f32_16x16x32_bf16(a, b, c, 0, 0, 0)

// ---------------- phase 1 of step t: hm_raw = h@wmh_raw, m = xm*hm*scmx*scmh ---------
__global__ __launch_bounds__(1024, 4)
void ph1_k(const unsigned short* __restrict__ wmhp, const unsigned short* __restrict__ wmxp,
           const unsigned short* __restrict__ xe, const unsigned short* __restrict__ hpk,
           const float* __restrict__ scmh, const float* __restrict__ scmx,
           unsigned short* __restrict__ mpk, int t) {
  const int g = blockIdx.x;
  const int tid = threadIdx.x;
  const int w = tid >> 6, l = tid & 63;
  const int lo = l & 15, hi = l >> 4;

  __shared__ float part[16][32][16];
  __shared__ float xmS[32][16];

  const s16x8* wmh_g = (const s16x8*)(wmhp + (size_t)g * 128 * 512);
  const s16x8* wmx_g = (const s16x8*)(wmxp + (size_t)g * 2 * 512);
  const s16x8* hp = (const s16x8*)hpk;

  f32x4 a0 = {0.f, 0.f, 0.f, 0.f}, a1 = {0.f, 0.f, 0.f, 0.f};
  const int cb = w * 8;
  {
    s16x8 wbuf[4], pa[4], pb[4];
#pragma unroll
    for (int q = 0; q < 4; ++q) {
      wbuf[q] = wmh_g[(cb + q) * 64 + l];
      pa[q] = hp[(cb + q) * 128 + l];
      pb[q] = hp[(cb + q) * 128 + 64 + l];
    }
#pragma unroll
    for (int q = 0; q < 8; ++q) {
      const int r = q & 3;
      s16x8 bf = wbuf[r], af = pa[r], gf = pb[r];
      if (q < 4) {
        wbuf[r] = wmh_g[(cb + q + 4) * 64 + l];
        pa[r] = hp[(cb + q + 4) * 128 + l];
        pb[r] = hp[(cb + q + 4) * 128 + 64 + l];
      }
      a0 = MFMA(af, bf, a0);
      a1 = MFMA(gf, bf, a1);
    }
  }
#pragma unroll
  for (int r = 0; r < 4; ++r) {
    part[w][4 * hi + r][lo] = a0[r];
    part[w][16 + 4 * hi + r][lo] = a1[r];
  }
  if (w == 0) {  // xm_raw = x_t @ wmx_raw (K=64)
    f32x4 x0 = {0.f, 0.f, 0.f, 0.f}, x1 = {0.f, 0.f, 0.f, 0.f};
    const s16x8* xep = (const s16x8*)(xe + (size_t)t * 2048);
#pragma unroll
    for (int c2 = 0; c2 < 2; ++c2) {
      s16x8 bf = wmx_g[c2 * 64 + l];
      x0 = MFMA(xep[c2 * 128 + l], bf, x0);
      x1 = MFMA(xep[c2 * 128 + 64 + l], bf, x1);
    }
#pragma unroll
    for (int r = 0; r < 4; ++r) {
      xmS[4 * hi + r][lo] = x0[r];
      xmS[16 + 4 * hi + r][lo] = x1[r];
    }
  }
  __syncthreads();
  if (tid < 512) {
    const int eb = tid >> 4, c = tid & 15;
    const int ej = g * 16 + c;
    float hm = 0.f;
#pragma unroll
    for (int k = 0; k < 16; ++k) hm += part[k][eb][c];
    mpk[apoff(eb, ej)] = f2bf(xmS[eb][c] * hm * (scmh[ej] * scmx[ej]));
  }
}

// ---------------- phase 2 of step t: z = scx*(x@wx) + sch*(m@wh) + b ; update --------
__global__ __launch_bounds__(1024, 4)
void ph2_k(const unsigned short* __restrict__ whp, const unsigned short* __restrict__ wxp,
           const unsigned short* __restrict__ xe, const float* __restrict__ bias,
           const float* __restrict__ sch, const float* __restrict__ scx,
           const float* __restrict__ Mm, const unsigned short* __restrict__ mpk,
           unsigned short* __restrict__ hpk, float* __restrict__ cst,
           float* __restrict__ hst, unsigned short* __restrict__ hflat,
           float* __restrict__ out, int t) {
  const int g = blockIdx.x;
  const int tid = threadIdx.x;
  const int w = tid >> 6, l = tid & 63;
  const int lo = l & 15, hi = l >> 4;
  const int gate = w & 3, ks = w >> 2;

  __shared__ float part[16][32][16];
  __shared__ float xpart[4][32][16];

  const s16x8* wh_w = (const s16x8*)(whp + (size_t)(g * 4 + gate) * 128 * 512);
  const s16x8* wx_w = (const s16x8*)(wxp + (size_t)(g * 4 + gate) * 2 * 512);
  const s16x8* mp = (const s16x8*)mpk;

  f32x4 z0 = {0.f, 0.f, 0.f, 0.f}, z1 = {0.f, 0.f, 0.f, 0.f};
  const int cb = ks * 32;
  {
    s16x8 wbuf[4], pa[4], pb[4];
#pragma unroll
    for (int q = 0; q < 4; ++q) {
      wbuf[q] = wh_w[(cb + q) * 64 + l];
      pa[q] = mp[(cb + q) * 128 + l];
      pb[q] = mp[(cb + q) * 128 + 64 + l];
    }
#pragma unroll
    for (int q = 0; q < 32; ++q) {
      const int r = q & 3;
      s16x8 bf = wbuf[r], af = pa[r], gf = pb[r];
      if (q < 28) {
        wbuf[r] = wh_w[(cb + q + 4) * 64 + l];
        pa[r] = mp[(cb + q + 4) * 128 + l];
        pb[r] = mp[(cb + q + 4) * 128 + 64 + l];
      }
      z0 = MFMA(af, bf, z0);
      z1 = MFMA(gf, bf, z1);
    }
  }
  if (ks == 0) {  // x @ wx_raw contribution (K=64), kept separate for scx scaling
    f32x4 x0 = {0.f, 0.f, 0.f, 0.f}, x1 = {0.f, 0.f, 0.f, 0.f};
    const s16x8* xep = (const s16x8*)(xe + (size_t)t * 2048);
#pragma unroll
    for (int c2 = 0; c2 < 2; ++c2) {
      s16x8 bf = wx_w[c2 * 64 + l];
      x0 = MFMA(xep[c2 * 128 + l], bf, x0);
      x1 = MFMA(xep[c2 * 128 + 64 + l], bf, x1);
    }
#pragma unroll
    for (int r = 0; r < 4; ++r) {
      xpart[gate][4 * hi + r][lo] = x0[r];
      xpart[gate][16 + 4 * hi + r][lo] = x1[r];
    }
  }
#pragma unroll
  for (int r = 0; r < 4; ++r) {
    part[w][4 * hi + r][lo] = z0[r];
    part[w][16 + 4 * hi + r][lo] = z1[r];
  }
  __syncthreads();
  if (tid < 512) {
    const int eb = tid >> 4, c = tid & 15;
    const int ej = g * 16 + c;
    float zh, iv, fv, ov, uv;
    zh = part[0][eb][c] + part[4][eb][c] + part[8][eb][c] + part[12][eb][c];
    iv = zh * sch[ej] + xpart[0][eb][c] * scx[ej] + bias[ej];
    zh = part[1][eb][c] + part[5][eb][c] + part[9][eb][c] + part[13][eb][c];
    fv = zh * sch[4096 + ej] + xpart[1][eb][c] * scx[4096 + ej] + bias[4096 + ej];
    zh = part[2][eb][c] + part[6][eb][c] + part[10][eb][c] + part[14][eb][c];
    ov = zh * sch[8192 + ej] + xpart[2][eb][c] * scx[8192 + ej] + bias[8192 + ej];
    zh = part[3][eb][c] + part[7][eb][c] + part[11][eb][c] + part[15][eb][c];
    uv = zh * sch[12288 + ej] + xpart[3][eb][c] * scx[12288 + ej] + bias[12288 + ej];
    iv = 1.f / (1.f + __expf(-iv));
    fv = 1.f / (1.f + __expf(-fv));
    ov = 1.f / (1.f + __expf(-ov));
    uv = tanhf(uv);
    size_t sj = (size_t)eb * HID + ej;
    float cp = cst[sj], hpv = hst[sj];
    float ct = fv * cp + iv * uv;
    float ht = ov * tanhf(ct);
    float mt = Mm[eb * NTIME + t];
    float cn = ct * mt + cp * (1.f - mt);
    float hn = ht * mt + hpv * (1.f - mt);
    cst[sj] = cn;
    hst[sj] = hn;
    out[((size_t)t * NBATCH + eb) * HID + ej] = cn;
    unsigned short hb = f2bf(hn);
    // packed A-fragment write for logits: tile = eb*4 + (t>>4), row-in-tile = t&15
    {
      int tle = eb * 4 + (t >> 4);
      int r16 = t & 15;
      int kk2 = ej & 31;
      int lane2 = r16 | (((kk2 >> 3) & 3) << 4);
      hflat[(size_t)tle * 65536 + (size_t)(ej >> 5) * 512 + lane2 * 8 + (kk2 & 7)] = hb;
    }
    hpk[apoff(eb, ej)] = hb;
    if (t == NTIME - 1) {
      out[(size_t)NTIME * NBATCH * HID + sj] = cn;
      out[(size_t)NTIME * NBATCH * HID + NBATCH * HID + sj] = hn;
    }
  }
}

// ---------------- logits = hflat @ w_out + b_out, packed-A ([2048,4096]x[4096,256]) --
__global__ __launch_bounds__(256)
void logits_k(const unsigned short* __restrict__ hpA,
              const unsigned short* __restrict__ woutp,
              const float* __restrict__ bout, float* __restrict__ out) {
  int tle = blockIdx.x >> 1, ch = blockIdx.x & 1;
  int tid = threadIdx.x, w = tid >> 6, l = tid & 63;
  int lo = l & 15, hi = l >> 4;
  const s16x8* ap = (const s16x8*)(hpA + (size_t)tle * 65536);
  const s16x8* wp = (const s16x8*)woutp;
  f32x4 acc[2] = {{0.f,0.f,0.f,0.f},{0.f,0.f,0.f,0.f}};
  const int nt0 = ch * 8 + w * 2;
#pragma unroll 4
  for (int c = 0; c < 128; ++c) {
    s16x8 af = ap[c * 64 + l];
    acc[0] = MFMA(af, wp[((nt0 + 0) * 128 + c) * 64 + l], acc[0]);
    acc[1] = MFMA(af, wp[((nt0 + 1) * 128 + c) * 64 + l], acc[1]);
  }
  int r0 = tle * 16;
#pragma unroll
  for (int q = 0; q < 2; ++q) {
    int col = (nt0 + q) * 16 + lo;
    float bo = bout[col];
#pragma unroll
    for (int r = 0; r < 4; ++r)
      out[(size_t)(r0 + 4 * hi + r) * NVOCAB + col] = acc[q][r] + bo;
  }
}

extern "C" void kernel_launch(void* const* d_in, const int* in_sizes, int n_in,
                              void* d_out, int out_size, void* d_ws, size_t ws_size,
                              hipStream_t stream) {
  const int*   X    = (const int*)d_in[0];
  const float* Mm   = (const float*)d_in[1];
  const float* S    = (const float*)d_in[2];
  const float* embd = (const float*)d_in[3];
  const float* wx   = (const float*)d_in[4];
  const float* wh   = (const float*)d_in[5];
  const float* wmx  = (const float*)d_in[6];
  const float* wmh  = (const float*)d_in[7];
  const float* b    = (const float*)d_in[8];
  const float* gx   = (const float*)d_in[9];
  const float* gh   = (const float*)d_in[10];
  const float* gmx  = (const float*)d_in[11];
  const float* gmh  = (const float*)d_in[12];
  const float* wout = (const float*)d_in[13];
  const float* bout = (const float*)d_in[14];
  float* out = (float*)d_out;
  char* ws = (char*)d_ws;

  size_t cur = 0;
  auto alloc = [&](size_t bytes) { size_t o = cur; cur += (bytes + 255) & ~size_t(255); return o; };
  unsigned short* WHP   = (unsigned short*)(ws + alloc((size_t)1024 * 128 * 512 * 2)); // 128MB
  unsigned short* WMHP  = (unsigned short*)(ws + alloc((size_t)256 * 128 * 512 * 2));  // 32MB
  unsigned short* WXP   = (unsigned short*)(ws + alloc((size_t)1024 * 2 * 512 * 2));   // 2MB
  unsigned short* WMXP  = (unsigned short*)(ws + alloc((size_t)256 * 2 * 512 * 2));    // 0.5MB
  unsigned short* WOUTP = (unsigned short*)(ws + alloc((size_t)16 * 128 * 512 * 2));   // 2MB
  unsigned short* XE    = (unsigned short*)(ws + alloc((size_t)64 * 2048 * 2));        // 256KB
  unsigned short* MPK   = (unsigned short*)(ws + alloc((size_t)32 * 4096 * 2));        // 256KB
  unsigned short* HPK   = (unsigned short*)(ws + alloc((size_t)32 * 4096 * 2));        // 256KB
  float* CST            = (float*)(ws + alloc((size_t)32 * 4096 * 4));
  float* HST            = (float*)(ws + alloc((size_t)32 * 4096 * 4));
  unsigned short* HFLAT = (unsigned short*)(ws + alloc((size_t)2048 * 4096 * 2));      // 16MB
  float* SCH            = (float*)(ws + alloc((size_t)16384 * 4));
  float* SCX            = (float*)(ws + alloc((size_t)16384 * 4));
  float* SCMH           = (float*)(ws + alloc((size_t)4096 * 4));
  float* SCMX           = (float*)(ws + alloc((size_t)4096 * 4));
  (void)ws_size; (void)in_sizes; (void)n_in; (void)out_size;

  // one-pass: pack raw weights to bf16 fragments + compute weight-norm scales
  packs_k<<<1024, 256, 0, stream>>>(wh,   gh,  WHP,   SCH,  G4,    4096, 2, 128);
  packs_k<<<256,  256, 0, stream>>>(wmh,  gmh, WMHP,  SCMH, HID,   0,    0, 128);
  packs_k<<<1024, 256, 0, stream>>>(wx,   gx,  WXP,   SCX,  G4,    4096, 2, 2);
  packs_k<<<256,  256, 0, stream>>>(wmx,  gmx, WMXP,  SCMX, HID,   0,    0, 2);
  packs_k<<<16,   256, 0, stream>>>(wout, nullptr, WOUTP, nullptr, NVOCAB, 0, 0, 128);

  xepack_k<<<64, 256, 0, stream>>>(X, embd, XE);
  init_k<<<512, 256, 0, stream>>>(S, CST, HST, HPK);

  // 64 steps, 2 kernels per step — stream ordering replaces the grid barrier
  for (int t = 0; t < NTIME; ++t) {
    ph1_k<<<256, 1024, 0, stream>>>(WMHP, WMXP, XE, HPK, SCMH, SCMX, MPK, t);
    ph2_k<<<256, 1024, 0, stream>>>(WHP, WXP, XE, b, SCH, SCX, Mm, MPK, HPK, CST, HST,
                                    HFLAT, out, t);
  }

  logits_k<<<256, 256, 0, stream>>>(HFLAT, WOUTP, bout,
                                    out + (size_t)NTIME * NBATCH * HID + 2 * NBATCH * HID);
}